// Round 6
// baseline (136.834 us; speedup 1.0000x reference)
//
#include <hip/hip_runtime.h>

// HilbertFlatten: out[s] = x[hilbert_decode(s)] for (256,256,256) f32.
// 32 consecutive curve points per thread (4 chunks of 8 = 4 2x2x2 cubes).
// ONE probe-decode (undo-loop iterations bit=5..0, masks read bits>=2 which
// are shared by all 32 points) yields affine map (A,c) for the passive bits
// 0 and 1. Iteration bit=6 (chunk-dependent, closed-form gray masks) is
// applied per-chunk as a byte map M6 before A. Loads: 16 independent float2
// gathers issued before any use (8KB/wave in flight). Stores: nontemporal.

typedef float f32x4 __attribute__((ext_vector_type(4)));

__global__ __launch_bounds__(256) void hilbert_g32_kernel(
    const float* __restrict__ x, float* __restrict__ out) {
    // XCD-chunked bijective swizzle (gridDim.x divisible by 8).
    unsigned nb = blockIdx.x;
    unsigned cpx = gridDim.x >> 3;
    unsigned b = (nb & 7u) * cpx + (nb >> 3);
    unsigned tid = b * 256u + threadIdx.x;
    unsigned S = tid << 5;                   // base curve index, mult of 32

    unsigned g = S ^ (S >> 1);
    unsigned G[3];
#pragma unroll
    for (int d = 0; d < 3; ++d) {
        unsigned v = (g >> (2 - d)) & 0x00249249u;
        v = (v ^ (v >> 2)) & 0x030C30C3u;
        v = (v ^ (v >> 4)) & 0x0300F00Fu;
        v = (v ^ (v >> 8)) & 0x000000FFu;
        G[d] = v;
    }
    // Probe channels: bits 8..10 identity basis, bit 11 affine constant.
    G[0] |= 0x100u; G[1] |= 0x200u; G[2] |= 0x400u;

    // Undo-loop iterations bit=5..0 ONLY (bit=6 handled per-chunk below).
    // Masks read integer bits 2..7 (shared across the 32 points); bits 0,1
    // and the probe bits ride passively -> affine map recoverable.
#pragma unroll
    for (int bit = 5; bit >= 0; --bit) {
        const unsigned low = ((1u << (7 - bit)) - 1u) | 0x0F00u;
#pragma unroll
        for (int dim = 2; dim >= 0; --dim) {
            unsigned m = (G[dim] >> (7 - bit)) & 1u;
            unsigned diff = (G[0] ^ G[dim]) & low;
            unsigned t = diff & (m - 1u);
            G[0] ^= ((0u - m) & low) ^ t;
            G[dim] ^= t;
        }
    }

    // Affine map rows as 0/-1 masks: out[d] = c[d] ^ XOR_e A[d][e]&in[e].
    unsigned cm[3], a0m[3], a1m[3], a2m[3];
#pragma unroll
    for (int d = 0; d < 3; ++d) {
        unsigned cd = 0u - ((G[d] >> 11) & 1u);
        cm[d] = cd;
        a0m[d] = (0u - ((G[d] >> 8) & 1u)) ^ cd;
        a1m[d] = (0u - ((G[d] >> 9) & 1u)) ^ cd;
        a2m[d] = (0u - ((G[d] >> 10) & 1u)) ^ cd;
    }

    unsigned S5 = (S >> 5) & 1u, S6 = (S >> 6) & 1u;
    unsigned u0 = S5 ^ S6;                   // initial G0.bit1 (all chunks)

    unsigned bases[4], Bb[4][3];
#pragma unroll
    for (int c = 0; c < 4; ++c) {
        unsigned c0 = (unsigned)c & 1u, c1 = ((unsigned)c >> 1) & 1u;
        unsigned u2 = c0 ^ c1;               // initial G2.bit1
        unsigned u1 = c1 ^ S5;               // initial G1.bit1
        // Initial bit-0 patterns over r=0..7: G0.b0=r2^c0, G1.b0=r1^r2,
        // G2.b0=r0^r1.
        unsigned V0 = 0xF0u ^ ((0u - c0) & 0xFFu);
        unsigned V1 = 0x3Cu, V2 = 0x66u;
        // M6 = undo iteration bit=6 (modifies bit0 only; masks = init bit1):
        unsigned mm = (0u - u2) & 0xFFu;     // dim=2: invert or swap V0<->V2
        unsigned t = (V0 ^ V2) & (mm ^ 0xFFu);
        V0 ^= mm ^ t;  V2 ^= t;
        mm = (0u - u1) & 0xFFu;              // dim=1: invert or swap V0<->V1
        t = (V0 ^ V1) & (mm ^ 0xFFu);
        V0 ^= mm ^ t;  V1 ^= t;
        V0 ^= (0u - u0) & 0xFFu;             // dim=0: conditional invert
        // Final coord bit0 bytes: B[d] = A row d applied to (V0,V1,V2) ^ c.
#pragma unroll
        for (int d = 0; d < 3; ++d)
            Bb[c][d] = ((a0m[d] & V0) ^ (a1m[d] & V1) ^ (a2m[d] & V2)
                        ^ cm[d]) & 0xFFu;
        // Final coord bit1 (constant within the chunk's 2x2x2 cube):
        unsigned b1x = ((a0m[0] & u0) ^ (a1m[0] & u1) ^ (a2m[0] & u2) ^ cm[0]) & 1u;
        unsigned b1y = ((a0m[1] & u0) ^ (a1m[1] & u1) ^ (a2m[1] & u2) ^ cm[1]) & 1u;
        unsigned b1z = ((a0m[2] & u0) ^ (a1m[2] & u1) ^ (a2m[2] & u2) ^ cm[2]) & 1u;
        unsigned cx = (G[0] & 0xFCu) | (b1x << 1);
        unsigned cy = (G[1] & 0xFCu) | (b1y << 1);
        unsigned cz = (G[2] & 0xFCu) | (b1z << 1);
        bases[c] = (cx << 16) | (cy << 8) | cz;   // bit0s zero -> 8B aligned
    }

    // Issue ALL 16 loads before any use (max outstanding bytes).
    float2 p[4][4];
#pragma unroll
    for (int c = 0; c < 4; ++c) {
        const float2* xp = (const float2*)(x + bases[c]);
        p[c][0] = xp[0];               // (i=0,j=0)
        p[c][1] = xp[128];             // (i=0,j=1): +256 floats
        p[c][2] = xp[32768];           // (i=1,j=0): +65536 floats
        p[c][3] = xp[32768 + 128];     // (i=1,j=1)
    }

    // Resolve curve order + store.
#pragma unroll
    for (int c = 0; c < 4; ++c) {
        float o8[8];
#pragma unroll
        for (int r = 0; r < 8; ++r) {
            unsigned f0 = (Bb[c][0] >> r) & 1u;   // x bit
            unsigned f1 = (Bb[c][1] >> r) & 1u;   // y bit
            unsigned f2 = (Bb[c][2] >> r) & 1u;   // z bit
            float2 t0 = f1 ? p[c][1] : p[c][0];
            float2 t1 = f1 ? p[c][3] : p[c][2];
            float2 t  = f0 ? t1 : t0;
            o8[r] = f2 ? t.y : t.x;
        }
        f32x4* o4 = (f32x4*)(out + S + 8u * (unsigned)c);
        f32x4 lo = {o8[0], o8[1], o8[2], o8[3]};
        f32x4 hi = {o8[4], o8[5], o8[6], o8[7]};
        __builtin_nontemporal_store(lo, o4);
        __builtin_nontemporal_store(hi, o4 + 1);
    }
}

extern "C" void kernel_launch(void* const* d_in, const int* in_sizes, int n_in,
                              void* d_out, int out_size, void* d_ws, size_t ws_size,
                              hipStream_t stream) {
    const float* x = (const float*)d_in[0];
    float* out = (float*)d_out;
    unsigned n = (unsigned)out_size;            // 16777216
    unsigned threads = n >> 5;                  // 524288 (32 pts/thread)
    unsigned blocks = threads / 256u;           // 2048 (divisible by 8)
    hilbert_g32_kernel<<<blocks, 256, 0, stream>>>(x, out);
}

// Round 7
// 40.207 us; speedup vs baseline: 3.4032x; 3.4032x over previous
//
#include <hip/hip_runtime.h>

// HilbertFlatten: out[s] = x[hilbert_decode(s)] for (256,256,256) f32.
// 32 consecutive curve points per thread (4 chunks of 8 = 4 2x2x2 cubes).
// ONE probe-decode (undo-loop iterations bit=5..0, masks read bits>=2 which
// are shared by all 32 points) yields affine map (A,c) for the passive bits
// 0 and 1. Iteration bit=6 (chunk-dependent, closed-form gray masks) is
// applied per-chunk as a byte map M6 before A. Loads: 16 independent float2
// gathers issued before any use (8KB/wave in flight). Stores: plain float4
// (through L2 — nontemporal caused 3x write amplification via partial-line
// writes at 128B lane stride; L2 coalesces them).

typedef float f32x4 __attribute__((ext_vector_type(4)));

__global__ __launch_bounds__(256) void hilbert_g32_kernel(
    const float* __restrict__ x, float* __restrict__ out) {
    // XCD-chunked bijective swizzle (gridDim.x divisible by 8).
    unsigned nb = blockIdx.x;
    unsigned cpx = gridDim.x >> 3;
    unsigned b = (nb & 7u) * cpx + (nb >> 3);
    unsigned tid = b * 256u + threadIdx.x;
    unsigned S = tid << 5;                   // base curve index, mult of 32

    unsigned g = S ^ (S >> 1);
    unsigned G[3];
#pragma unroll
    for (int d = 0; d < 3; ++d) {
        unsigned v = (g >> (2 - d)) & 0x00249249u;
        v = (v ^ (v >> 2)) & 0x030C30C3u;
        v = (v ^ (v >> 4)) & 0x0300F00Fu;
        v = (v ^ (v >> 8)) & 0x000000FFu;
        G[d] = v;
    }
    // Probe channels: bits 8..10 identity basis, bit 11 affine constant.
    G[0] |= 0x100u; G[1] |= 0x200u; G[2] |= 0x400u;

    // Undo-loop iterations bit=5..0 ONLY (bit=6 handled per-chunk below).
#pragma unroll
    for (int bit = 5; bit >= 0; --bit) {
        const unsigned low = ((1u << (7 - bit)) - 1u) | 0x0F00u;
#pragma unroll
        for (int dim = 2; dim >= 0; --dim) {
            unsigned m = (G[dim] >> (7 - bit)) & 1u;
            unsigned diff = (G[0] ^ G[dim]) & low;
            unsigned t = diff & (m - 1u);
            G[0] ^= ((0u - m) & low) ^ t;
            G[dim] ^= t;
        }
    }

    // Affine map rows as 0/-1 masks: out[d] = c[d] ^ XOR_e A[d][e]&in[e].
    unsigned cm[3], a0m[3], a1m[3], a2m[3];
#pragma unroll
    for (int d = 0; d < 3; ++d) {
        unsigned cd = 0u - ((G[d] >> 11) & 1u);
        cm[d] = cd;
        a0m[d] = (0u - ((G[d] >> 8) & 1u)) ^ cd;
        a1m[d] = (0u - ((G[d] >> 9) & 1u)) ^ cd;
        a2m[d] = (0u - ((G[d] >> 10) & 1u)) ^ cd;
    }

    unsigned S5 = (S >> 5) & 1u, S6 = (S >> 6) & 1u;
    unsigned u0 = S5 ^ S6;                   // initial G0.bit1 (all chunks)

    unsigned bases[4], Bb[4][3];
#pragma unroll
    for (int c = 0; c < 4; ++c) {
        unsigned c0 = (unsigned)c & 1u, c1 = ((unsigned)c >> 1) & 1u;
        unsigned u2 = c0 ^ c1;               // initial G2.bit1
        unsigned u1 = c1 ^ S5;               // initial G1.bit1
        unsigned V0 = 0xF0u ^ ((0u - c0) & 0xFFu);
        unsigned V1 = 0x3Cu, V2 = 0x66u;
        // M6 = undo iteration bit=6 (modifies bit0 only; masks = init bit1):
        unsigned mm = (0u - u2) & 0xFFu;     // dim=2: invert or swap V0<->V2
        unsigned t = (V0 ^ V2) & (mm ^ 0xFFu);
        V0 ^= mm ^ t;  V2 ^= t;
        mm = (0u - u1) & 0xFFu;              // dim=1: invert or swap V0<->V1
        t = (V0 ^ V1) & (mm ^ 0xFFu);
        V0 ^= mm ^ t;  V1 ^= t;
        V0 ^= (0u - u0) & 0xFFu;             // dim=0: conditional invert
#pragma unroll
        for (int d = 0; d < 3; ++d)
            Bb[c][d] = ((a0m[d] & V0) ^ (a1m[d] & V1) ^ (a2m[d] & V2)
                        ^ cm[d]) & 0xFFu;
        unsigned b1x = ((a0m[0] & u0) ^ (a1m[0] & u1) ^ (a2m[0] & u2) ^ cm[0]) & 1u;
        unsigned b1y = ((a0m[1] & u0) ^ (a1m[1] & u1) ^ (a2m[1] & u2) ^ cm[1]) & 1u;
        unsigned b1z = ((a0m[2] & u0) ^ (a1m[2] & u1) ^ (a2m[2] & u2) ^ cm[2]) & 1u;
        unsigned cx = (G[0] & 0xFCu) | (b1x << 1);
        unsigned cy = (G[1] & 0xFCu) | (b1y << 1);
        unsigned cz = (G[2] & 0xFCu) | (b1z << 1);
        bases[c] = (cx << 16) | (cy << 8) | cz;   // bit0s zero -> 8B aligned
    }

    // Issue ALL 16 loads before any use (max outstanding bytes).
    float2 p[4][4];
#pragma unroll
    for (int c = 0; c < 4; ++c) {
        const float2* xp = (const float2*)(x + bases[c]);
        p[c][0] = xp[0];               // (i=0,j=0)
        p[c][1] = xp[128];             // (i=0,j=1): +256 floats
        p[c][2] = xp[32768];           // (i=1,j=0): +65536 floats
        p[c][3] = xp[32768 + 128];     // (i=1,j=1)
    }

    // Resolve curve order + store.
#pragma unroll
    for (int c = 0; c < 4; ++c) {
        float o8[8];
#pragma unroll
        for (int r = 0; r < 8; ++r) {
            unsigned f0 = (Bb[c][0] >> r) & 1u;   // x bit
            unsigned f1 = (Bb[c][1] >> r) & 1u;   // y bit
            unsigned f2 = (Bb[c][2] >> r) & 1u;   // z bit
            float2 t0 = f1 ? p[c][1] : p[c][0];
            float2 t1 = f1 ? p[c][3] : p[c][2];
            float2 t  = f0 ? t1 : t0;
            o8[r] = f2 ? t.y : t.x;
        }
        f32x4* o4 = (f32x4*)(out + S + 8u * (unsigned)c);
        o4[0] = (f32x4){o8[0], o8[1], o8[2], o8[3]};
        o4[1] = (f32x4){o8[4], o8[5], o8[6], o8[7]};
    }
}

extern "C" void kernel_launch(void* const* d_in, const int* in_sizes, int n_in,
                              void* d_out, int out_size, void* d_ws, size_t ws_size,
                              hipStream_t stream) {
    const float* x = (const float*)d_in[0];
    float* out = (float*)d_out;
    unsigned n = (unsigned)out_size;            // 16777216
    unsigned threads = n >> 5;                  // 524288 (32 pts/thread)
    unsigned blocks = threads / 256u;           // 2048 (divisible by 8)
    hilbert_g32_kernel<<<blocks, 256, 0, stream>>>(x, out);
}

// Round 8
// 25.487 us; speedup vs baseline: 5.3688x; 1.5776x over previous
//
#include <hip/hip_runtime.h>

// HilbertFlatten: out[s] = x[hilbert_decode(s)] for (256,256,256) f32.
// R2 structure (8 pts/thread, probe-decode, 4x float2 cube load) + shuffle-
// paired stores: each of the wave's two store instructions writes a fully
// contiguous 1KB (lane i <- thread i>>1's half via __shfl), so every 64B
// line is covered by ONE instruction -> nontemporal full-line streaming
// stores are safe (no partial-line RMW) and bypass L2 allocation.

typedef float f32x4 __attribute__((ext_vector_type(4)));

__global__ __launch_bounds__(256) void hilbert_g8s_kernel(
    const float* __restrict__ x, float* __restrict__ out, unsigned ngroups) {
    // XCD-chunked bijective swizzle (gridDim.x divisible by 8).
    unsigned nb = blockIdx.x;
    unsigned cpx = gridDim.x >> 3;
    unsigned b = (nb & 7u) * cpx + (nb >> 3);
    unsigned tid = threadIdx.x;
    unsigned gid = b * 256u + tid;
    if (gid >= ngroups) return;          // never taken (exact grid)
    unsigned S = gid << 3;
    unsigned lane = tid & 63u;

    unsigned g = S ^ (S >> 1);
    unsigned G[3];
#pragma unroll
    for (int d = 0; d < 3; ++d) {
        unsigned v = (g >> (2 - d)) & 0x00249249u;
        v = (v ^ (v >> 2)) & 0x030C30C3u;
        v = (v ^ (v >> 4)) & 0x0300F00Fu;
        v = (v ^ (v >> 8)) & 0x000000FFu;
        G[d] = v;
    }
    // Probe channels: bits 8..10 identity basis, bit 11 affine constant.
    G[0] |= 0x100u; G[1] |= 0x200u; G[2] |= 0x400u;

#pragma unroll
    for (int bit = 6; bit >= 0; --bit) {
        const unsigned low = ((1u << (7 - bit)) - 1u) | 0x0F00u;
#pragma unroll
        for (int dim = 2; dim >= 0; --dim) {
            unsigned m = (G[dim] >> (7 - bit)) & 1u;
            unsigned diff = (G[0] ^ G[dim]) & low;
            unsigned t = diff & (m - 1u);
            G[0] ^= ((0u - m) & low) ^ t;
            G[dim] ^= t;
        }
    }

    // Per-offset init bit0 patterns over r=0..7.
    unsigned s3m = 0u - ((S >> 3) & 1u);
    unsigned V0 = (0xF0u ^ s3m) & 0xFFu;
    const unsigned V1 = 0x3Cu, V2 = 0x66u;

    unsigned B[3];
#pragma unroll
    for (int d = 0; d < 3; ++d) {
        unsigned cd = 0u - ((G[d] >> 11) & 1u);
        unsigned a0 = (0u - ((G[d] >> 8) & 1u)) ^ cd;
        unsigned a1 = (0u - ((G[d] >> 9) & 1u)) ^ cd;
        unsigned a2 = (0u - ((G[d] >> 10) & 1u)) ^ cd;
        B[d] = ((a0 & V0) ^ (a1 & V1) ^ (a2 & V2) ^ cd) & 0xFFu;
    }

    unsigned baseflat = ((G[0] & 0xFEu) << 16) | ((G[1] & 0xFEu) << 8)
                      | (G[2] & 0xFEu);

    // Load own 2x2x2 cube as 4 z-pair float2s.
    const float2* xp = (const float2*)(x + baseflat);
    float2 p00 = xp[0];
    float2 p01 = xp[128];
    float2 p10 = xp[32768];
    float2 p11 = xp[32768 + 128];

    float o8[8];
#pragma unroll
    for (int r = 0; r < 8; ++r) {
        unsigned f0 = (B[0] >> r) & 1u;
        unsigned f1 = (B[1] >> r) & 1u;
        unsigned f2 = (B[2] >> r) & 1u;
        float2 t0 = f1 ? p01 : p00;
        float2 t1 = f1 ? p11 : p10;
        float2 t  = f0 ? t1 : t0;
        o8[r] = f2 ? t.y : t.x;
    }

    // Shuffle-paired fully-contiguous stores.
    // Store A: floats [WB + 4*lane, +4) = thread (lane>>1)'s o8[(lane&1)*4..].
    // Store B: floats [WB + 256 + 4*lane, +4) = thread 32+(lane>>1)'s half.
    int src1 = (int)(lane >> 1);
    int src2 = (int)(32u + (lane >> 1));
    bool hi = (lane & 1u) != 0u;
    float vA[4], vB[4];
#pragma unroll
    for (int j = 0; j < 4; ++j) {
        float a = __shfl(o8[j], src1, 64);
        float bb = __shfl(o8[4 + j], src1, 64);
        vA[j] = hi ? bb : a;
        float c = __shfl(o8[j], src2, 64);
        float d = __shfl(o8[4 + j], src2, 64);
        vB[j] = hi ? d : c;
    }
    unsigned WB = (gid & ~63u) << 3;     // wave's first curve point
    f32x4* oA = (f32x4*)(out + WB + 4u * lane);
    f32x4* oB = (f32x4*)(out + WB + 256u + 4u * lane);
    __builtin_nontemporal_store((f32x4){vA[0], vA[1], vA[2], vA[3]}, oA);
    __builtin_nontemporal_store((f32x4){vB[0], vB[1], vB[2], vB[3]}, oB);
}

extern "C" void kernel_launch(void* const* d_in, const int* in_sizes, int n_in,
                              void* d_out, int out_size, void* d_ws, size_t ws_size,
                              hipStream_t stream) {
    const float* x = (const float*)d_in[0];
    float* out = (float*)d_out;
    unsigned n = (unsigned)out_size;               // 16777216
    unsigned ngroups = n >> 3;                     // 2097152
    unsigned blocks = (ngroups + 255u) / 256u;     // 8192 (divisible by 8)
    hilbert_g8s_kernel<<<blocks, 256, 0, stream>>>(x, out, ngroups);
}